// Round 3
// baseline (606.856 us; speedup 1.0000x reference)
//
#include <hip/hip_runtime.h>
#include <hip/hip_bf16.h>
#include <cmath>

#define B_ 2
#define H_ 8
#define S_ 2048
#define D_ 64
#define TQ 16
#define TK 64
#define KCHUNKS 4
#define TPC ((S_ / TK) / KCHUNKS)   // 8 k-tiles of 64 keys per chunk

typedef __bf16 bf16x8 __attribute__((ext_vector_type(8)));
typedef float  f32x4  __attribute__((ext_vector_type(4)));

// 272B rows = 17 x 16B units: odd unit count staggers banks across rows.
// Score reads (float4), score writes (b32), packed-att writes (b64) and
// A-frag reads (b128, rotate-swizzled) are all conflict-free/2-way.
#define SB_STRIDE 68

#define NK ((size_t)B_ * H_ * S_ * D_)   // 2,097,152 elements

// ---------------- prep 1: K -> bf16 hi/lo (split-bf16 for fp32-grade QK) ----------------
__global__ __launch_bounds__(256)
void prep_k(const float* __restrict__ kg, __bf16* __restrict__ khi, __bf16* __restrict__ klo)
{
    const size_t i = ((size_t)blockIdx.x * 256 + threadIdx.x) * 8;
    float4 f0 = ((const float4*)(kg + i))[0];
    float4 f1 = ((const float4*)(kg + i))[1];
    float fv[8] = {f0.x, f0.y, f0.z, f0.w, f1.x, f1.y, f1.z, f1.w};
    bf16x8 hi, lo;
    #pragma unroll
    for (int j = 0; j < 8; ++j) {
        __bf16 h = (__bf16)fv[j];
        hi[j] = h;
        lo[j] = (__bf16)(fv[j] - (float)h);
    }
    *(bf16x8*)(khi + i) = hi;
    *(bf16x8*)(klo + i) = lo;
}

// ---------------- prep 2: V -> bf16 transposed vt[b][h][d][s] ----------------
__global__ __launch_bounds__(256)
void prep_vt(const float* __restrict__ vg, __bf16* __restrict__ vt)
{
    __shared__ float tile[64][65];
    const int bh = blockIdx.x >> 5;   // 0..15 = b*H+h
    const int kt = blockIdx.x & 31;   // 64-key tile
    const int t  = threadIdx.x;
    {
        const int key = t >> 2, seg = t & 3;
        const float* src = vg + ((size_t)bh * S_ + kt * 64 + key) * D_ + seg * 16;
        #pragma unroll
        for (int i = 0; i < 4; ++i) {
            float4 f = ((const float4*)src)[i];
            tile[key][seg * 16 + i * 4 + 0] = f.x;
            tile[key][seg * 16 + i * 4 + 1] = f.y;
            tile[key][seg * 16 + i * 4 + 2] = f.z;
            tile[key][seg * 16 + i * 4 + 3] = f.w;
        }
    }
    __syncthreads();
    {
        const int d = t >> 2, seg = t & 3;
        bf16x8 o0, o1;
        #pragma unroll
        for (int j = 0; j < 8; ++j) o0[j] = (__bf16)tile[seg * 16 + j][d];
        #pragma unroll
        for (int j = 0; j < 8; ++j) o1[j] = (__bf16)tile[seg * 16 + 8 + j][d];
        __bf16* dst = vt + ((size_t)bh * D_ + d) * S_ + kt * 64 + seg * 16;
        *(bf16x8*)dst       = o0;
        *((bf16x8*)dst + 1) = o1;
    }
}

// ---------------- main fused kernel ----------------
__global__ __launch_bounds__(256, 4)
void attn_fused(const float* __restrict__ qg,
                const __bf16* __restrict__ khi_g, const __bf16* __restrict__ klo_g,
                const __bf16* __restrict__ vt_g,  const int* __restrict__ maskg,
                float* __restrict__ zout, float* __restrict__ attout)
{
    // single LDS buffer: fp32 scores, then in-place swizzled bf16 att (34,816 B -> 4 blocks/CU)
    __shared__ __align__(16) float sbuf[H_][TQ][SB_STRIDE];

    const int tid  = threadIdx.x;
    const int lane = tid & 63;
    const int wave = tid >> 6;      // wave handles heads 2w, 2w+1
    const int n16  = lane & 15;
    const int quad = lane >> 4;

    // chunk in LOW bits: round-robin XCD dispatch => each XCD sees one (chunk,b)
    // pair, so its 1.5 MB K/V slice stays L2-resident.
    const int bi    = blockIdx.x;
    const int chunk = bi & (KCHUNKS - 1);
    const int b     = (bi >> 2) & 1;
    const int qt    = bi >> 3;        // 0..127
    const int q0    = qt * TQ;

    const float scale = 0.35355339059327373f;  // 1/sqrt(H=8) -- k.shape[1] trap!

    // Q fragments, hi/lo split-bf16 (scaled), converted ONCE per block
    bf16x8 qhi[2][2], qlo[2][2];
    #pragma unroll
    for (int hh = 0; hh < 2; ++hh) {
        const int h = wave * 2 + hh;
        const float* qp = qg + (size_t)((b * H_ + h) * S_ + q0 + n16) * D_;
        #pragma unroll
        for (int kk = 0; kk < 2; ++kk) {
            const float4* p = (const float4*)(qp + kk * 32 + quad * 8);
            float4 f0 = p[0], f1 = p[1];
            float fv[8] = {f0.x, f0.y, f0.z, f0.w, f1.x, f1.y, f1.z, f1.w};
            bf16x8 hi, lo;
            #pragma unroll
            for (int j = 0; j < 8; ++j) {
                float fs = fv[j] * scale;
                __bf16 h16 = (__bf16)fs;
                hi[j] = h16;
                lo[j] = (__bf16)(fs - (float)h16);
            }
            qhi[hh][kk] = hi; qlo[hh][kk] = lo;
        }
    }

    f32x4 acc[2][4];
    #pragma unroll
    for (int hh = 0; hh < 2; ++hh)
        #pragma unroll
        for (int d = 0; d < 4; ++d)
            acc[hh][d] = (f32x4){0.f, 0.f, 0.f, 0.f};

    // softmax-phase mapping: one q-row + one float4 of 4 keys per thread
    const int sqq = tid >> 4;       // 0..15
    const int sk4 = tid & 15;       // 4-key column group

    const int* mrow = maskg + (size_t)(b * S_ + q0 + sqq) * S_ + chunk * (TK * TPC) + sk4 * 4;
    int4 mcur = *(const int4*)mrow;        // mask for kt=0, loaded before the loop

    for (int kt = 0; kt < TPC; ++kt) {
        const int k0 = chunk * (TK * TPC) + kt * TK;

        // prefetch next iteration's mask: a full iteration of latency hiding
        const int kn = (kt + 1 < TPC) ? (kt + 1) : kt;
        int4 mnext = *(const int4*)(mrow + kn * TK);

        // ---- QK^T: 3-term split-bf16 MFMA into registers ----
        f32x4 c[2][4];
        #pragma unroll
        for (int hh = 0; hh < 2; ++hh) {
            const int h = wave * 2 + hh;
            #pragma unroll
            for (int ks = 0; ks < 4; ++ks) {
                const size_t krow = ((size_t)(b * H_ + h) * S_ + k0 + ks * 16 + n16) * D_
                                    + quad * 8;
                f32x4 cc = (f32x4){0.f, 0.f, 0.f, 0.f};
                #pragma unroll
                for (int kk = 0; kk < 2; ++kk) {
                    bf16x8 khiv = *(const bf16x8*)(khi_g + krow + kk * 32);
                    bf16x8 klov = *(const bf16x8*)(klo_g + krow + kk * 32);
                    cc = __builtin_amdgcn_mfma_f32_16x16x32_bf16(qhi[hh][kk], khiv, cc, 0, 0, 0);
                    cc = __builtin_amdgcn_mfma_f32_16x16x32_bf16(qlo[hh][kk], khiv, cc, 0, 0, 0);
                    cc = __builtin_amdgcn_mfma_f32_16x16x32_bf16(qhi[hh][kk], klov, cc, 0, 0, 0);
                }
                c[hh][ks] = cc;
            }
        }

        __syncthreads();   // (b3) previous iteration's PV has finished reading att in sbuf
                           //      (QK loads+MFMAs above overlap that PV)

        #pragma unroll
        for (int hh = 0; hh < 2; ++hh) {
            const int h = wave * 2 + hh;
            #pragma unroll
            for (int ks = 0; ks < 4; ++ks)
                #pragma unroll
                for (int r = 0; r < 4; ++r)
                    sbuf[h][quad * 4 + r][ks * 16 + n16] = c[hh][ks][r];
        }

        __syncthreads();   // (b1) scores visible to all waves

        // ---- softmax ACROSS HEADS (axis=1) + mask ----
        // att stored to global INLINE per head (value computed -> stored -> dead).
        // Round-2 lesson: keeping all 8 f32x4 live across the next barrier spilled
        // 128B/thread to scratch = +268MB fetch +268MB write. Never again.
        {
            f32x4 sv[H_];
            f32x4 mx = (f32x4){-INFINITY, -INFINITY, -INFINITY, -INFINITY};
            #pragma unroll
            for (int h = 0; h < H_; ++h) {
                sv[h] = *(const f32x4*)&sbuf[h][sqq][sk4 * 4];
                #pragma unroll
                for (int j = 0; j < 4; ++j) mx[j] = fmaxf(mx[j], sv[h][j]);
            }
            f32x4 sum = (f32x4){0.f, 0.f, 0.f, 0.f};
            #pragma unroll
            for (int h = 0; h < H_; ++h)
                #pragma unroll
                for (int j = 0; j < 4; ++j) {
                    sv[h][j] = __expf(sv[h][j] - mx[j]);
                    sum[j] += sv[h][j];
                }
            f32x4 inv;
            #pragma unroll
            for (int j = 0; j < 4; ++j) inv[j] = 1.0f / sum[j];
            const int mm[4] = {mcur.x, mcur.y, mcur.z, mcur.w};
            const int physw = ((sk4 >> 1) + 2 * (sqq & 3)) & 7;   // rotate-swizzle unit
            #pragma unroll
            for (int h = 0; h < H_; ++h) {
                f32x4 a;
                #pragma unroll
                for (int j = 0; j < 4; ++j)
                    // all-heads-masked => ties => uniform softmax = 1/8
                    a[j] = (mm[j] == 0) ? 0.125f : sv[h][j] * inv[j];
                // fp32 att -> global immediately (16B store, fire-and-forget)
                *(f32x4*)&attout[(size_t)((b * H_ + h) * S_ + q0 + sqq) * S_ + k0 + sk4 * 4] = a;
                // pack 4 bf16; in-place over consumed scores. Safe: row sqq is
                // touched only by 16 threads of ONE wave; per-wave LDS ops are
                // in-order, and all reads precede all writes in program order.
                union { __bf16 b4[4]; uint2 u2; } pk;
                #pragma unroll
                for (int j = 0; j < 4; ++j) pk.b4[j] = (__bf16)a[j];
                *(uint2*)((char*)&sbuf[h][sqq][0] + physw * 16 + (sk4 & 1) * 8) = pk.u2;
            }
        }

        __syncthreads();   // (b2) packed att visible

        // ---- PV: A = swizzled bf16 att from LDS, B = pre-transposed V^T ----
        #pragma unroll
        for (int hh = 0; hh < 2; ++hh) {
            const int h = wave * 2 + hh;
            #pragma unroll
            for (int kk = 0; kk < 2; ++kk) {
                const int physr = ((kk * 4 + quad) + 2 * (n16 & 3)) & 7;
                bf16x8 af = *(const bf16x8*)((const char*)&sbuf[h][n16][0] + physr * 16);
                #pragma unroll
                for (int dsb = 0; dsb < 4; ++dsb) {
                    bf16x8 bv = *(const bf16x8*)(vt_g
                        + ((size_t)(b * H_ + h) * D_ + dsb * 16 + n16) * S_
                        + k0 + kk * 32 + quad * 8);
                    acc[hh][dsb] = __builtin_amdgcn_mfma_f32_16x16x32_bf16(af, bv, acc[hh][dsb], 0, 0, 0);
                }
            }
        }

        mcur = mnext;
    }

    // ---- epilogue: accumulate partial z across k-chunks via device atomics ----
    #pragma unroll
    for (int hh = 0; hh < 2; ++hh) {
        const int h = wave * 2 + hh;
        #pragma unroll
        for (int dsb = 0; dsb < 4; ++dsb)
            #pragma unroll
            for (int r = 0; r < 4; ++r)
                atomicAdd(&zout[(size_t)((b * H_ + h) * S_ + q0 + quad * 4 + r) * D_
                                + dsb * 16 + n16],
                          acc[hh][dsb][r]);
    }
}

extern "C" void kernel_launch(void* const* d_in, const int* in_sizes, int n_in,
                              void* d_out, int out_size, void* d_ws, size_t ws_size,
                              hipStream_t stream) {
    const float* q    = (const float*)d_in[0];
    const float* k    = (const float*)d_in[1];
    const float* v    = (const float*)d_in[2];
    const int*   mask = (const int*)d_in[3];
    float* z   = (float*)d_out;
    float* att = (float*)d_out + NK;   // outputs: (z, att_score)

    // workspace layout: khi | klo | vt   (bf16 each, NK elements) = 12.6 MB
    __bf16* khi = (__bf16*)d_ws;
    __bf16* klo = khi + NK;
    __bf16* vt  = klo + NK;

    prep_k <<<dim3(NK / (256 * 8)), dim3(256), 0, stream>>>(k, khi, klo);
    prep_vt<<<dim3(B_ * H_ * (S_ / 64)), dim3(256), 0, stream>>>(v, vt);

    // z accumulated atomically across 4 k-chunks -> must start at zero
    hipMemsetAsync(z, 0, NK * sizeof(float), stream);

    attn_fused<<<dim3(KCHUNKS * B_ * (S_ / TQ)), dim3(256), 0, stream>>>(
        q, khi, klo, vt, mask, z, att);
}

// Round 4
// 603.302 us; speedup vs baseline: 1.0059x; 1.0059x over previous
//
#include <hip/hip_runtime.h>
#include <hip/hip_bf16.h>
#include <cmath>

#define B_ 2
#define H_ 8
#define S_ 2048
#define D_ 64
#define TQ 16
#define TK 64
#define KCHUNKS 4
#define TPC ((S_ / TK) / KCHUNKS)   // 8 k-tiles of 64 keys per chunk

typedef __bf16 bf16x8 __attribute__((ext_vector_type(8)));
typedef float  f32x4  __attribute__((ext_vector_type(4)));

// 272B rows = 17 x 16B units: odd unit count staggers banks across rows.
#define SB_STRIDE 68

#define NK ((size_t)B_ * H_ * S_ * D_)   // 2,097,152 elements

// ---------------- prep 1: K -> bf16 hi/lo (split-bf16 for fp32-grade QK) ----------------
__global__ __launch_bounds__(256)
void prep_k(const float* __restrict__ kg, __bf16* __restrict__ khi, __bf16* __restrict__ klo)
{
    const size_t i = ((size_t)blockIdx.x * 256 + threadIdx.x) * 8;
    float4 f0 = ((const float4*)(kg + i))[0];
    float4 f1 = ((const float4*)(kg + i))[1];
    float fv[8] = {f0.x, f0.y, f0.z, f0.w, f1.x, f1.y, f1.z, f1.w};
    bf16x8 hi, lo;
    #pragma unroll
    for (int j = 0; j < 8; ++j) {
        __bf16 h = (__bf16)fv[j];
        hi[j] = h;
        lo[j] = (__bf16)(fv[j] - (float)h);
    }
    *(bf16x8*)(khi + i) = hi;
    *(bf16x8*)(klo + i) = lo;
}

// ---------------- prep 2: V -> bf16 transposed vt[b][h][d][s] ----------------
__global__ __launch_bounds__(256)
void prep_vt(const float* __restrict__ vg, __bf16* __restrict__ vt)
{
    __shared__ float tile[64][65];
    const int bh = blockIdx.x >> 5;   // 0..15 = b*H+h
    const int kt = blockIdx.x & 31;   // 64-key tile
    const int t  = threadIdx.x;
    {
        const int key = t >> 2, seg = t & 3;
        const float* src = vg + ((size_t)bh * S_ + kt * 64 + key) * D_ + seg * 16;
        #pragma unroll
        for (int i = 0; i < 4; ++i) {
            float4 f = ((const float4*)src)[i];
            tile[key][seg * 16 + i * 4 + 0] = f.x;
            tile[key][seg * 16 + i * 4 + 1] = f.y;
            tile[key][seg * 16 + i * 4 + 2] = f.z;
            tile[key][seg * 16 + i * 4 + 3] = f.w;
        }
    }
    __syncthreads();
    {
        const int d = t >> 2, seg = t & 3;
        bf16x8 o0, o1;
        #pragma unroll
        for (int j = 0; j < 8; ++j) o0[j] = (__bf16)tile[seg * 16 + j][d];
        #pragma unroll
        for (int j = 0; j < 8; ++j) o1[j] = (__bf16)tile[seg * 16 + 8 + j][d];
        __bf16* dst = vt + ((size_t)bh * D_ + d) * S_ + kt * 64 + seg * 16;
        *(bf16x8*)dst       = o0;
        *((bf16x8*)dst + 1) = o1;
    }
}

// ---------------- main fused kernel ----------------
__global__ __launch_bounds__(256, 4)
void attn_fused(const float* __restrict__ qg,
                const __bf16* __restrict__ khi_g, const __bf16* __restrict__ klo_g,
                const __bf16* __restrict__ vt_g,  const int* __restrict__ maskg,
                float* __restrict__ zout, float* __restrict__ attout)
{
    // single LDS buffer: fp32 scores, then in-place swizzled bf16 att (34,816 B -> 4 blocks/CU)
    __shared__ __align__(16) float sbuf[H_][TQ][SB_STRIDE];

    const int tid  = threadIdx.x;
    const int lane = tid & 63;
    const int wave = tid >> 6;      // wave handles heads 2w, 2w+1
    const int n16  = lane & 15;
    const int quad = lane >> 4;

    // chunk in LOW bits: each XCD sees one (chunk,b) pair -> K/V slice L2/L3-local
    const int bi    = blockIdx.x;
    const int chunk = bi & (KCHUNKS - 1);
    const int b     = (bi >> 2) & 1;
    const int qt    = bi >> 3;        // 0..127
    const int q0    = qt * TQ;

    const float scale = 0.35355339059327373f;  // 1/sqrt(H=8) -- k.shape[1] trap!

    // Q fragments, hi/lo split-bf16 (scaled), converted ONCE per block
    bf16x8 qhi[2][2], qlo[2][2];
    #pragma unroll
    for (int hh = 0; hh < 2; ++hh) {
        const int h = wave * 2 + hh;
        const float* qp = qg + (size_t)((b * H_ + h) * S_ + q0 + n16) * D_;
        #pragma unroll
        for (int kk = 0; kk < 2; ++kk) {
            const float4* p = (const float4*)(qp + kk * 32 + quad * 8);
            float4 f0 = p[0], f1 = p[1];
            float fv[8] = {f0.x, f0.y, f0.z, f0.w, f1.x, f1.y, f1.z, f1.w};
            bf16x8 hi, lo;
            #pragma unroll
            for (int j = 0; j < 8; ++j) {
                float fs = fv[j] * scale;
                __bf16 h16 = (__bf16)fs;
                hi[j] = h16;
                lo[j] = (__bf16)(fs - (float)h16);
            }
            qhi[hh][kk] = hi; qlo[hh][kk] = lo;
        }
    }

    f32x4 acc[2][4];
    #pragma unroll
    for (int hh = 0; hh < 2; ++hh)
        #pragma unroll
        for (int d = 0; d < 4; ++d)
            acc[hh][d] = (f32x4){0.f, 0.f, 0.f, 0.f};

    // softmax-phase mapping: one q-row + one float4 of 4 keys per thread
    const int sqq = tid >> 4;       // 0..15
    const int sk4 = tid & 15;       // 4-key column group

    const int* mrow = maskg + (size_t)(b * S_ + q0 + sqq) * S_ + chunk * (TK * TPC) + sk4 * 4;
    int4 mcur = *(const int4*)mrow;        // mask for kt=0, loaded before the loop

    for (int kt = 0; kt < TPC; ++kt) {
        const int k0 = chunk * (TK * TPC) + kt * TK;

        // prefetch next iteration's mask: a full iteration of latency hiding
        const int kn = (kt + 1 < TPC) ? (kt + 1) : kt;
        int4 mnext = *(const int4*)(mrow + kn * TK);

        __syncthreads();   // (b3) previous iteration's PV done reading sbuf
                           //      (first iter: trivial)

        // ---- QK^T: 3-term split-bf16 MFMA; scores written to LDS INLINE ----
        // Round-3 lesson: holding c[2][4] (32 VGPRs) across a barrier spilled
        // ~150B/thread/iter to scratch (+250MB fetch, +300MB write). Each cc
        // must die inside its ks iteration.
        #pragma unroll
        for (int hh = 0; hh < 2; ++hh) {
            const int h = wave * 2 + hh;
            #pragma unroll
            for (int ks = 0; ks < 4; ++ks) {
                const size_t krow = ((size_t)(b * H_ + h) * S_ + k0 + ks * 16 + n16) * D_
                                    + quad * 8;
                f32x4 cc = (f32x4){0.f, 0.f, 0.f, 0.f};
                #pragma unroll
                for (int kk = 0; kk < 2; ++kk) {
                    bf16x8 khiv = *(const bf16x8*)(khi_g + krow + kk * 32);
                    bf16x8 klov = *(const bf16x8*)(klo_g + krow + kk * 32);
                    cc = __builtin_amdgcn_mfma_f32_16x16x32_bf16(qhi[hh][kk], khiv, cc, 0, 0, 0);
                    cc = __builtin_amdgcn_mfma_f32_16x16x32_bf16(qlo[hh][kk], khiv, cc, 0, 0, 0);
                    cc = __builtin_amdgcn_mfma_f32_16x16x32_bf16(qhi[hh][kk], klov, cc, 0, 0, 0);
                }
                #pragma unroll
                for (int r = 0; r < 4; ++r)
                    sbuf[h][quad * 4 + r][ks * 16 + n16] = cc[r];
            }
        }

        __syncthreads();   // (b1) scores visible to all waves

        // ---- softmax ACROSS HEADS (axis=1) + mask; att stored inline ----
        {
            f32x4 sv[H_];
            f32x4 mx = (f32x4){-INFINITY, -INFINITY, -INFINITY, -INFINITY};
            #pragma unroll
            for (int h = 0; h < H_; ++h) {
                sv[h] = *(const f32x4*)&sbuf[h][sqq][sk4 * 4];
                #pragma unroll
                for (int j = 0; j < 4; ++j) mx[j] = fmaxf(mx[j], sv[h][j]);
            }
            f32x4 sum = (f32x4){0.f, 0.f, 0.f, 0.f};
            #pragma unroll
            for (int h = 0; h < H_; ++h)
                #pragma unroll
                for (int j = 0; j < 4; ++j) {
                    sv[h][j] = __expf(sv[h][j] - mx[j]);
                    sum[j] += sv[h][j];
                }
            f32x4 inv;
            #pragma unroll
            for (int j = 0; j < 4; ++j) inv[j] = 1.0f / sum[j];
            const int mm[4] = {mcur.x, mcur.y, mcur.z, mcur.w};
            const int physw = ((sk4 >> 1) + 2 * (sqq & 3)) & 7;   // rotate-swizzle unit
            #pragma unroll
            for (int h = 0; h < H_; ++h) {
                f32x4 a;
                #pragma unroll
                for (int j = 0; j < 4; ++j)
                    // all-heads-masked => ties => uniform softmax = 1/8
                    a[j] = (mm[j] == 0) ? 0.125f : sv[h][j] * inv[j];
                // fp32 att -> global immediately (16B store, value then dead)
                *(f32x4*)&attout[(size_t)((b * H_ + h) * S_ + q0 + sqq) * S_ + k0 + sk4 * 4] = a;
                // pack 4 bf16; in-place over consumed scores. Safe: row sqq is
                // touched only by 16 threads of ONE wave; per-wave LDS ops are
                // in-order, and all reads precede all writes in program order.
                union { __bf16 b4[4]; uint2 u2; } pk;
                #pragma unroll
                for (int j = 0; j < 4; ++j) pk.b4[j] = (__bf16)a[j];
                *(uint2*)((char*)&sbuf[h][sqq][0] + physw * 16 + (sk4 & 1) * 8) = pk.u2;
            }
        }

        __syncthreads();   // (b2) packed att visible

        // ---- PV: A = swizzled bf16 att from LDS, B = pre-transposed V^T ----
        #pragma unroll
        for (int hh = 0; hh < 2; ++hh) {
            const int h = wave * 2 + hh;
            #pragma unroll
            for (int kk = 0; kk < 2; ++kk) {
                const int physr = ((kk * 4 + quad) + 2 * (n16 & 3)) & 7;
                bf16x8 af = *(const bf16x8*)((const char*)&sbuf[h][n16][0] + physr * 16);
                #pragma unroll
                for (int dsb = 0; dsb < 4; ++dsb) {
                    bf16x8 bv = *(const bf16x8*)(vt_g
                        + ((size_t)(b * H_ + h) * D_ + dsb * 16 + n16) * S_
                        + k0 + kk * 32 + quad * 8);
                    acc[hh][dsb] = __builtin_amdgcn_mfma_f32_16x16x32_bf16(af, bv, acc[hh][dsb], 0, 0, 0);
                }
            }
        }

        mcur = mnext;
    }

    // ---- epilogue: accumulate partial z across k-chunks via device atomics ----
    #pragma unroll
    for (int hh = 0; hh < 2; ++hh) {
        const int h = wave * 2 + hh;
        #pragma unroll
        for (int dsb = 0; dsb < 4; ++dsb)
            #pragma unroll
            for (int r = 0; r < 4; ++r)
                atomicAdd(&zout[(size_t)((b * H_ + h) * S_ + q0 + quad * 4 + r) * D_
                                + dsb * 16 + n16],
                          acc[hh][dsb][r]);
    }
}

extern "C" void kernel_launch(void* const* d_in, const int* in_sizes, int n_in,
                              void* d_out, int out_size, void* d_ws, size_t ws_size,
                              hipStream_t stream) {
    const float* q    = (const float*)d_in[0];
    const float* k    = (const float*)d_in[1];
    const float* v    = (const float*)d_in[2];
    const int*   mask = (const int*)d_in[3];
    float* z   = (float*)d_out;
    float* att = (float*)d_out + NK;   // outputs: (z, att_score)

    // workspace layout: khi | klo | vt   (bf16 each, NK elements) = 12.6 MB
    __bf16* khi = (__bf16*)d_ws;
    __bf16* klo = khi + NK;
    __bf16* vt  = klo + NK;

    prep_k <<<dim3(NK / (256 * 8)), dim3(256), 0, stream>>>(k, khi, klo);
    prep_vt<<<dim3(B_ * H_ * (S_ / 64)), dim3(256), 0, stream>>>(v, vt);

    // z accumulated atomically across 4 k-chunks -> must start at zero
    hipMemsetAsync(z, 0, NK * sizeof(float), stream);

    attn_fused<<<dim3(KCHUNKS * B_ * (S_ / TQ)), dim3(256), 0, stream>>>(
        q, khi, klo, vt, mask, z, att);
}

// Round 5
// 552.531 us; speedup vs baseline: 1.0983x; 1.0919x over previous
//
#include <hip/hip_runtime.h>
#include <hip/hip_bf16.h>
#include <cmath>

#define B_ 2
#define H_ 8
#define S_ 2048
#define D_ 64
#define TQ 16
#define TK 64
#define KCHUNKS 8
#define TPC ((S_ / TK) / KCHUNKS)   // 4 k-tiles of 64 keys per chunk

typedef __bf16 bf16x8 __attribute__((ext_vector_type(8)));
typedef float  f32x4  __attribute__((ext_vector_type(4)));

// 272B rows = 17 x 16B units: odd unit count staggers banks across rows.
#define SB_STRIDE 68

#define NK ((size_t)B_ * H_ * S_ * D_)   // 2,097,152 elements

// ---------------- prep 1: K -> bf16 hi/lo (split-bf16 for fp32-grade QK) ----------------
__global__ __launch_bounds__(256)
void prep_k(const float* __restrict__ kg, __bf16* __restrict__ khi, __bf16* __restrict__ klo)
{
    const size_t i = ((size_t)blockIdx.x * 256 + threadIdx.x) * 8;
    float4 f0 = ((const float4*)(kg + i))[0];
    float4 f1 = ((const float4*)(kg + i))[1];
    float fv[8] = {f0.x, f0.y, f0.z, f0.w, f1.x, f1.y, f1.z, f1.w};
    bf16x8 hi, lo;
    #pragma unroll
    for (int j = 0; j < 8; ++j) {
        __bf16 h = (__bf16)fv[j];
        hi[j] = h;
        lo[j] = (__bf16)(fv[j] - (float)h);
    }
    *(bf16x8*)(khi + i) = hi;
    *(bf16x8*)(klo + i) = lo;
}

// ---------------- prep 2: V -> bf16 transposed vt[b][h][d][s] ----------------
__global__ __launch_bounds__(256)
void prep_vt(const float* __restrict__ vg, __bf16* __restrict__ vt)
{
    __shared__ float tile[64][65];
    const int bh = blockIdx.x >> 5;   // 0..15 = b*H+h
    const int kt = blockIdx.x & 31;   // 64-key tile
    const int t  = threadIdx.x;
    {
        const int key = t >> 2, seg = t & 3;
        const float* src = vg + ((size_t)bh * S_ + kt * 64 + key) * D_ + seg * 16;
        #pragma unroll
        for (int i = 0; i < 4; ++i) {
            float4 f = ((const float4*)src)[i];
            tile[key][seg * 16 + i * 4 + 0] = f.x;
            tile[key][seg * 16 + i * 4 + 1] = f.y;
            tile[key][seg * 16 + i * 4 + 2] = f.z;
            tile[key][seg * 16 + i * 4 + 3] = f.w;
        }
    }
    __syncthreads();
    {
        const int d = t >> 2, seg = t & 3;
        bf16x8 o0, o1;
        #pragma unroll
        for (int j = 0; j < 8; ++j) o0[j] = (__bf16)tile[seg * 16 + j][d];
        #pragma unroll
        for (int j = 0; j < 8; ++j) o1[j] = (__bf16)tile[seg * 16 + 8 + j][d];
        __bf16* dst = vt + ((size_t)bh * D_ + d) * S_ + kt * 64 + seg * 16;
        *(bf16x8*)dst       = o0;
        *((bf16x8*)dst + 1) = o1;
    }
}

// ---------------- main fused kernel ----------------
__global__ __launch_bounds__(256, 4)
void attn_fused(const float* __restrict__ qg,
                const __bf16* __restrict__ khi_g, const __bf16* __restrict__ klo_g,
                const __bf16* __restrict__ vt_g,  const int* __restrict__ maskg,
                float* __restrict__ zout, float* __restrict__ attout)
{
    // single LDS buffer: fp32 scores, then in-place swizzled bf16 att (34,816 B -> 4 blocks/CU)
    __shared__ __align__(16) float sbuf[H_][TQ][SB_STRIDE];

    const int tid  = threadIdx.x;
    const int lane = tid & 63;
    const int wave = tid >> 6;      // wave handles heads 2w, 2w+1
    const int n16  = lane & 15;
    const int quad = lane >> 4;

    // ROUND-0 grid mapping (measured-good): chunk in HIGH bits. The 8 z-partials
    // of a q-tile land on the SAME XCD (bi%8 invariant in chunk) -> z atomics stay
    // L2-local; each XCD holds a small interleaved K/V hot set that survives L2.
    // Round-2's chunk-in-low-bits mapping cost +250MB fetch / +316MB write.
    const int bi    = blockIdx.x;
    const int b     = bi & 1;
    const int qt    = (bi >> 1) & 127;
    const int chunk = bi >> 8;
    const int q0    = qt * TQ;

    const float scale = 0.35355339059327373f;  // 1/sqrt(H=8) -- k.shape[1] trap!

    // Q fragments, hi/lo split-bf16 (scaled), converted ONCE per block
    bf16x8 qhi[2][2], qlo[2][2];
    #pragma unroll
    for (int hh = 0; hh < 2; ++hh) {
        const int h = wave * 2 + hh;
        const float* qp = qg + (size_t)((b * H_ + h) * S_ + q0 + n16) * D_;
        #pragma unroll
        for (int kk = 0; kk < 2; ++kk) {
            const float4* p = (const float4*)(qp + kk * 32 + quad * 8);
            float4 f0 = p[0], f1 = p[1];
            float fv[8] = {f0.x, f0.y, f0.z, f0.w, f1.x, f1.y, f1.z, f1.w};
            bf16x8 hi, lo;
            #pragma unroll
            for (int j = 0; j < 8; ++j) {
                float fs = fv[j] * scale;
                __bf16 h16 = (__bf16)fs;
                hi[j] = h16;
                lo[j] = (__bf16)(fs - (float)h16);
            }
            qhi[hh][kk] = hi; qlo[hh][kk] = lo;
        }
    }

    f32x4 acc[2][4];
    #pragma unroll
    for (int hh = 0; hh < 2; ++hh)
        #pragma unroll
        for (int d = 0; d < 4; ++d)
            acc[hh][d] = (f32x4){0.f, 0.f, 0.f, 0.f};

    // softmax-phase mapping: one q-row + one float4 of 4 keys per thread
    const int sqq = tid >> 4;       // 0..15
    const int sk4 = tid & 15;       // 4-key column group

    const int* mrow = maskg + (size_t)(b * S_ + q0 + sqq) * S_ + chunk * (TK * TPC) + sk4 * 4;
    int4 mcur = *(const int4*)mrow;        // mask for kt=0, loaded before the loop

    for (int kt = 0; kt < TPC; ++kt) {
        const int k0 = chunk * (TK * TPC) + kt * TK;

        // prefetch next iteration's mask: a full iteration of latency hiding
        const int kn = (kt + 1 < TPC) ? (kt + 1) : kt;
        int4 mnext = *(const int4*)(mrow + kn * TK);

        __syncthreads();   // (b3) previous iteration's PV done reading sbuf
                           //      (first iter: trivial)

        // ---- QK^T: 3-term split-bf16 MFMA; scores written to LDS INLINE ----
        // (cc dies inside its ks iteration -- no accumulators across barriers)
        #pragma unroll
        for (int hh = 0; hh < 2; ++hh) {
            const int h = wave * 2 + hh;
            #pragma unroll
            for (int ks = 0; ks < 4; ++ks) {
                const size_t krow = ((size_t)(b * H_ + h) * S_ + k0 + ks * 16 + n16) * D_
                                    + quad * 8;
                f32x4 cc = (f32x4){0.f, 0.f, 0.f, 0.f};
                #pragma unroll
                for (int kk = 0; kk < 2; ++kk) {
                    bf16x8 khiv = *(const bf16x8*)(khi_g + krow + kk * 32);
                    bf16x8 klov = *(const bf16x8*)(klo_g + krow + kk * 32);
                    cc = __builtin_amdgcn_mfma_f32_16x16x32_bf16(qhi[hh][kk], khiv, cc, 0, 0, 0);
                    cc = __builtin_amdgcn_mfma_f32_16x16x32_bf16(qlo[hh][kk], khiv, cc, 0, 0, 0);
                    cc = __builtin_amdgcn_mfma_f32_16x16x32_bf16(qhi[hh][kk], klov, cc, 0, 0, 0);
                }
                #pragma unroll
                for (int r = 0; r < 4; ++r)
                    sbuf[h][quad * 4 + r][ks * 16 + n16] = cc[r];
            }
        }

        __syncthreads();   // (b1) scores visible to all waves

        // ---- softmax ACROSS HEADS (axis=1) + mask; att stored inline ----
        {
            f32x4 sv[H_];
            f32x4 mx = (f32x4){-INFINITY, -INFINITY, -INFINITY, -INFINITY};
            #pragma unroll
            for (int h = 0; h < H_; ++h) {
                sv[h] = *(const f32x4*)&sbuf[h][sqq][sk4 * 4];
                #pragma unroll
                for (int j = 0; j < 4; ++j) mx[j] = fmaxf(mx[j], sv[h][j]);
            }
            f32x4 sum = (f32x4){0.f, 0.f, 0.f, 0.f};
            #pragma unroll
            for (int h = 0; h < H_; ++h)
                #pragma unroll
                for (int j = 0; j < 4; ++j) {
                    sv[h][j] = __expf(sv[h][j] - mx[j]);
                    sum[j] += sv[h][j];
                }
            f32x4 inv;
            #pragma unroll
            for (int j = 0; j < 4; ++j) inv[j] = 1.0f / sum[j];
            const int mm[4] = {mcur.x, mcur.y, mcur.z, mcur.w};
            const int physw = ((sk4 >> 1) + 2 * (sqq & 3)) & 7;   // rotate-swizzle unit
            #pragma unroll
            for (int h = 0; h < H_; ++h) {
                f32x4 a;
                #pragma unroll
                for (int j = 0; j < 4; ++j)
                    // all-heads-masked => ties => uniform softmax = 1/8
                    a[j] = (mm[j] == 0) ? 0.125f : sv[h][j] * inv[j];
                // fp32 att -> global immediately (16B store, value then dead)
                *(f32x4*)&attout[(size_t)((b * H_ + h) * S_ + q0 + sqq) * S_ + k0 + sk4 * 4] = a;
                // pack 4 bf16; in-place over consumed scores. Safe: row sqq is
                // touched only by 16 threads of ONE wave; per-wave LDS ops are
                // in-order, and all reads precede all writes in program order.
                union { __bf16 b4[4]; uint2 u2; } pk;
                #pragma unroll
                for (int j = 0; j < 4; ++j) pk.b4[j] = (__bf16)a[j];
                *(uint2*)((char*)&sbuf[h][sqq][0] + physw * 16 + (sk4 & 1) * 8) = pk.u2;
            }
        }

        __syncthreads();   // (b2) packed att visible

        // ---- PV: A = swizzled bf16 att from LDS, B = pre-transposed V^T ----
        #pragma unroll
        for (int hh = 0; hh < 2; ++hh) {
            const int h = wave * 2 + hh;
            #pragma unroll
            for (int kk = 0; kk < 2; ++kk) {
                const int physr = ((kk * 4 + quad) + 2 * (n16 & 3)) & 7;
                bf16x8 af = *(const bf16x8*)((const char*)&sbuf[h][n16][0] + physr * 16);
                #pragma unroll
                for (int dsb = 0; dsb < 4; ++dsb) {
                    bf16x8 bv = *(const bf16x8*)(vt_g
                        + ((size_t)(b * H_ + h) * D_ + dsb * 16 + n16) * S_
                        + k0 + kk * 32 + quad * 8);
                    acc[hh][dsb] = __builtin_amdgcn_mfma_f32_16x16x32_bf16(af, bv, acc[hh][dsb], 0, 0, 0);
                }
            }
        }

        mcur = mnext;
    }

    // ---- epilogue: accumulate partial z across k-chunks via device atomics ----
    // (all 8 chunk-partials of a q-tile map to the same XCD -> L2-local atomics)
    #pragma unroll
    for (int hh = 0; hh < 2; ++hh) {
        const int h = wave * 2 + hh;
        #pragma unroll
        for (int dsb = 0; dsb < 4; ++dsb)
            #pragma unroll
            for (int r = 0; r < 4; ++r)
                atomicAdd(&zout[(size_t)((b * H_ + h) * S_ + q0 + quad * 4 + r) * D_
                                + dsb * 16 + n16],
                          acc[hh][dsb][r]);
    }
}

extern "C" void kernel_launch(void* const* d_in, const int* in_sizes, int n_in,
                              void* d_out, int out_size, void* d_ws, size_t ws_size,
                              hipStream_t stream) {
    const float* q    = (const float*)d_in[0];
    const float* k    = (const float*)d_in[1];
    const float* v    = (const float*)d_in[2];
    const int*   mask = (const int*)d_in[3];
    float* z   = (float*)d_out;
    float* att = (float*)d_out + NK;   // outputs: (z, att_score)

    // workspace layout: khi | klo | vt   (bf16 each, NK elements) = 12.6 MB
    __bf16* khi = (__bf16*)d_ws;
    __bf16* klo = khi + NK;
    __bf16* vt  = klo + NK;

    prep_k <<<dim3(NK / (256 * 8)), dim3(256), 0, stream>>>(k, khi, klo);
    prep_vt<<<dim3(B_ * H_ * (S_ / 64)), dim3(256), 0, stream>>>(v, vt);

    // z accumulated atomically across 8 k-chunks -> must start at zero
    hipMemsetAsync(z, 0, NK * sizeof(float), stream);

    attn_fused<<<dim3(KCHUNKS * B_ * (S_ / TQ)), dim3(256), 0, stream>>>(
        q, khi, klo, vt, mask, z, att);
}

// Round 6
// 547.032 us; speedup vs baseline: 1.1094x; 1.0101x over previous
//
#include <hip/hip_runtime.h>
#include <hip/hip_bf16.h>
#include <cmath>

#define B_ 2
#define H_ 8
#define S_ 2048
#define D_ 64
#define TQ 16
#define TK 64
#define KCHUNKS 8
#define TPC ((S_ / TK) / KCHUNKS)   // 4 k-tiles of 64 keys per chunk

typedef __bf16 bf16x8 __attribute__((ext_vector_type(8)));
typedef float  f32x4  __attribute__((ext_vector_type(4)));

// 272B rows = 17 x 16B units: odd unit count staggers banks across rows.
#define SB_STRIDE 68

#define NK ((size_t)B_ * H_ * S_ * D_)   // 2,097,152 elements

// ---------------- prep 1: K -> bf16 hi/lo (split-bf16 for fp32-grade QK) ----------------
__global__ __launch_bounds__(256)
void prep_k(const float* __restrict__ kg, __bf16* __restrict__ khi, __bf16* __restrict__ klo)
{
    const size_t i = ((size_t)blockIdx.x * 256 + threadIdx.x) * 8;
    float4 f0 = ((const float4*)(kg + i))[0];
    float4 f1 = ((const float4*)(kg + i))[1];
    float fv[8] = {f0.x, f0.y, f0.z, f0.w, f1.x, f1.y, f1.z, f1.w};
    bf16x8 hi, lo;
    #pragma unroll
    for (int j = 0; j < 8; ++j) {
        __bf16 h = (__bf16)fv[j];
        hi[j] = h;
        lo[j] = (__bf16)(fv[j] - (float)h);
    }
    *(bf16x8*)(khi + i) = hi;
    *(bf16x8*)(klo + i) = lo;
}

// ---------------- prep 2: V -> bf16 transposed vt[b][h][d][s] ----------------
__global__ __launch_bounds__(256)
void prep_vt(const float* __restrict__ vg, __bf16* __restrict__ vt)
{
    __shared__ float tile[64][65];
    const int bh = blockIdx.x >> 5;   // 0..15 = b*H+h
    const int kt = blockIdx.x & 31;   // 64-key tile
    const int t  = threadIdx.x;
    {
        const int key = t >> 2, seg = t & 3;
        const float* src = vg + ((size_t)bh * S_ + kt * 64 + key) * D_ + seg * 16;
        #pragma unroll
        for (int i = 0; i < 4; ++i) {
            float4 f = ((const float4*)src)[i];
            tile[key][seg * 16 + i * 4 + 0] = f.x;
            tile[key][seg * 16 + i * 4 + 1] = f.y;
            tile[key][seg * 16 + i * 4 + 2] = f.z;
            tile[key][seg * 16 + i * 4 + 3] = f.w;
        }
    }
    __syncthreads();
    {
        const int d = t >> 2, seg = t & 3;
        bf16x8 o0, o1;
        #pragma unroll
        for (int j = 0; j < 8; ++j) o0[j] = (__bf16)tile[seg * 16 + j][d];
        #pragma unroll
        for (int j = 0; j < 8; ++j) o1[j] = (__bf16)tile[seg * 16 + 8 + j][d];
        __bf16* dst = vt + ((size_t)bh * D_ + d) * S_ + kt * 64 + seg * 16;
        *(bf16x8*)dst       = o0;
        *((bf16x8*)dst + 1) = o1;
    }
}

// ---------------- main fused kernel ----------------
__global__ __launch_bounds__(256, 4)
void attn_fused(const float* __restrict__ qg,
                const __bf16* __restrict__ khi_g, const __bf16* __restrict__ klo_g,
                const __bf16* __restrict__ vt_g,  const int* __restrict__ maskg,
                float* __restrict__ zout, float* __restrict__ attout)
{
    // single LDS buffer: fp32 scores, then in-place swizzled bf16 att (34,816 B -> 4 blocks/CU)
    __shared__ __align__(16) float sbuf[H_][TQ][SB_STRIDE];

    const int tid  = threadIdx.x;
    const int lane = tid & 63;
    const int wave = tid >> 6;      // wave handles heads 2w, 2w+1
    const int n16  = lane & 15;
    const int quad = lane >> 4;

    // ROUND-0 grid mapping (measured-good): chunk in HIGH bits. The 8 z-partials
    // of a q-tile land on the SAME XCD -> z atomics stay L2-local; each XCD holds
    // a small interleaved K/V hot set that survives L2.
    const int bi    = blockIdx.x;
    const int b     = bi & 1;
    const int qt    = (bi >> 1) & 127;
    const int chunk = bi >> 8;
    const int q0    = qt * TQ;

    const float scale = 0.35355339059327373f;  // 1/sqrt(H=8) -- k.shape[1] trap!

    // Q fragments, hi/lo split-bf16 (scaled), converted ONCE per block
    bf16x8 qhi[2][2], qlo[2][2];
    #pragma unroll
    for (int hh = 0; hh < 2; ++hh) {
        const int h = wave * 2 + hh;
        const float* qp = qg + (size_t)((b * H_ + h) * S_ + q0 + n16) * D_;
        #pragma unroll
        for (int kk = 0; kk < 2; ++kk) {
            const float4* p = (const float4*)(qp + kk * 32 + quad * 8);
            float4 f0 = p[0], f1 = p[1];
            float fv[8] = {f0.x, f0.y, f0.z, f0.w, f1.x, f1.y, f1.z, f1.w};
            bf16x8 hi, lo;
            #pragma unroll
            for (int j = 0; j < 8; ++j) {
                float fs = fv[j] * scale;
                __bf16 h16 = (__bf16)fs;
                hi[j] = h16;
                lo[j] = (__bf16)(fs - (float)h16);
            }
            qhi[hh][kk] = hi; qlo[hh][kk] = lo;
        }
    }

    f32x4 acc[2][4];
    #pragma unroll
    for (int hh = 0; hh < 2; ++hh)
        #pragma unroll
        for (int d = 0; d < 4; ++d)
            acc[hh][d] = (f32x4){0.f, 0.f, 0.f, 0.f};

    // softmax-phase mapping: one q-row + one float4 of 4 keys per thread
    const int sqq = tid >> 4;       // 0..15
    const int sk4 = tid & 15;       // 4-key column group

    const int* mrow = maskg + (size_t)(b * S_ + q0 + sqq) * S_ + chunk * (TK * TPC) + sk4 * 4;
    int4 mcur = *(const int4*)mrow;        // mask for kt=0, loaded before the loop

    for (int kt = 0; kt < TPC; ++kt) {
        const int k0 = chunk * (TK * TPC) + kt * TK;

        // prefetch next iteration's mask: a full iteration of latency hiding
        const int kn = (kt + 1 < TPC) ? (kt + 1) : kt;
        int4 mnext = *(const int4*)(mrow + kn * TK);

        __syncthreads();   // (b3) previous iteration's PV done reading sbuf
                           //      (first iter: trivial)

        // ---- QK^T: 3-term split-bf16 MFMA; scores written to LDS INLINE ----
        // (cc dies inside its ks iteration -- no accumulators across barriers)
        #pragma unroll
        for (int hh = 0; hh < 2; ++hh) {
            const int h = wave * 2 + hh;
            #pragma unroll
            for (int ks = 0; ks < 4; ++ks) {
                const size_t krow = ((size_t)(b * H_ + h) * S_ + k0 + ks * 16 + n16) * D_
                                    + quad * 8;
                f32x4 cc = (f32x4){0.f, 0.f, 0.f, 0.f};
                #pragma unroll
                for (int kk = 0; kk < 2; ++kk) {
                    bf16x8 khiv = *(const bf16x8*)(khi_g + krow + kk * 32);
                    bf16x8 klov = *(const bf16x8*)(klo_g + krow + kk * 32);
                    cc = __builtin_amdgcn_mfma_f32_16x16x32_bf16(qhi[hh][kk], khiv, cc, 0, 0, 0);
                    cc = __builtin_amdgcn_mfma_f32_16x16x32_bf16(qlo[hh][kk], khiv, cc, 0, 0, 0);
                    cc = __builtin_amdgcn_mfma_f32_16x16x32_bf16(qhi[hh][kk], klov, cc, 0, 0, 0);
                }
                #pragma unroll
                for (int r = 0; r < 4; ++r)
                    sbuf[h][quad * 4 + r][ks * 16 + n16] = cc[r];
            }
        }

        __syncthreads();   // (b1) scores visible to all waves

        // ---- softmax ACROSS HEADS (axis=1), THREE-PASS over LDS ----
        // Round-5 lesson: sv[H_] (32 VGPRs) + qhi/qlo(32) + acc(32) exceeded the
        // 128-reg cap -> ~64B/thread/iter scratch round-trip (+27MB fetch,
        // +34MB write per iteration). Re-reading LDS and recomputing exp costs
        // ~32 VALU ops (VALU is 9% busy) and zero registers.
        {
            // pass 1: max across heads (one f32x4 temp)
            f32x4 mx = (f32x4){-INFINITY, -INFINITY, -INFINITY, -INFINITY};
            #pragma unroll
            for (int h = 0; h < H_; ++h) {
                f32x4 s = *(const f32x4*)&sbuf[h][sqq][sk4 * 4];
                #pragma unroll
                for (int j = 0; j < 4; ++j) mx[j] = fmaxf(mx[j], s[j]);
            }
            // pass 2: sum of exp (one f32x4 temp)
            f32x4 sum = (f32x4){0.f, 0.f, 0.f, 0.f};
            #pragma unroll
            for (int h = 0; h < H_; ++h) {
                f32x4 s = *(const f32x4*)&sbuf[h][sqq][sk4 * 4];
                #pragma unroll
                for (int j = 0; j < 4; ++j) sum[j] += __expf(s[j] - mx[j]);
            }
            f32x4 inv;
            #pragma unroll
            for (int j = 0; j < 4; ++j) inv[j] = 1.0f / sum[j];
            const int mm[4] = {mcur.x, mcur.y, mcur.z, mcur.w};
            const int physw = ((sk4 >> 1) + 2 * (sqq & 3)) & 7;   // rotate-swizzle unit
            // pass 3: recompute exp, mask, store att + pack bf16; value dies per h
            #pragma unroll
            for (int h = 0; h < H_; ++h) {
                f32x4 s = *(const f32x4*)&sbuf[h][sqq][sk4 * 4];
                f32x4 a;
                #pragma unroll
                for (int j = 0; j < 4; ++j)
                    // all-heads-masked => ties => uniform softmax = 1/8
                    a[j] = (mm[j] == 0) ? 0.125f : __expf(s[j] - mx[j]) * inv[j];
                // fp32 att -> global immediately (16B store, value then dead)
                *(f32x4*)&attout[(size_t)((b * H_ + h) * S_ + q0 + sqq) * S_ + k0 + sk4 * 4] = a;
                // pack 4 bf16 in-place. Safe: the pack for plane h happens after
                // this thread's read of plane h (program order, same wave); later
                // iterations read DIFFERENT planes h' > h.
                union { __bf16 b4[4]; uint2 u2; } pk;
                #pragma unroll
                for (int j = 0; j < 4; ++j) pk.b4[j] = (__bf16)a[j];
                *(uint2*)((char*)&sbuf[h][sqq][0] + physw * 16 + (sk4 & 1) * 8) = pk.u2;
            }
        }

        __syncthreads();   // (b2) packed att visible

        // ---- PV: A = swizzled bf16 att from LDS, B = pre-transposed V^T ----
        #pragma unroll
        for (int hh = 0; hh < 2; ++hh) {
            const int h = wave * 2 + hh;
            #pragma unroll
            for (int kk = 0; kk < 2; ++kk) {
                const int physr = ((kk * 4 + quad) + 2 * (n16 & 3)) & 7;
                bf16x8 af = *(const bf16x8*)((const char*)&sbuf[h][n16][0] + physr * 16);
                #pragma unroll
                for (int dsb = 0; dsb < 4; ++dsb) {
                    bf16x8 bv = *(const bf16x8*)(vt_g
                        + ((size_t)(b * H_ + h) * D_ + dsb * 16 + n16) * S_
                        + k0 + kk * 32 + quad * 8);
                    acc[hh][dsb] = __builtin_amdgcn_mfma_f32_16x16x32_bf16(af, bv, acc[hh][dsb], 0, 0, 0);
                }
            }
        }

        mcur = mnext;
    }

    // ---- epilogue: accumulate partial z across k-chunks via device atomics ----
    // (all 8 chunk-partials of a q-tile map to the same XCD -> L2-local atomics)
    #pragma unroll
    for (int hh = 0; hh < 2; ++hh) {
        const int h = wave * 2 + hh;
        #pragma unroll
        for (int dsb = 0; dsb < 4; ++dsb)
            #pragma unroll
            for (int r = 0; r < 4; ++r)
                atomicAdd(&zout[(size_t)((b * H_ + h) * S_ + q0 + quad * 4 + r) * D_
                                + dsb * 16 + n16],
                          acc[hh][dsb][r]);
    }
}

extern "C" void kernel_launch(void* const* d_in, const int* in_sizes, int n_in,
                              void* d_out, int out_size, void* d_ws, size_t ws_size,
                              hipStream_t stream) {
    const float* q    = (const float*)d_in[0];
    const float* k    = (const float*)d_in[1];
    const float* v    = (const float*)d_in[2];
    const int*   mask = (const int*)d_in[3];
    float* z   = (float*)d_out;
    float* att = (float*)d_out + NK;   // outputs: (z, att_score)

    // workspace layout: khi | klo | vt   (bf16 each, NK elements) = 12.6 MB
    __bf16* khi = (__bf16*)d_ws;
    __bf16* klo = khi + NK;
    __bf16* vt  = klo + NK;

    prep_k <<<dim3(NK / (256 * 8)), dim3(256), 0, stream>>>(k, khi, klo);
    prep_vt<<<dim3(B_ * H_ * (S_ / 64)), dim3(256), 0, stream>>>(v, vt);

    // z accumulated atomically across 8 k-chunks -> must start at zero
    hipMemsetAsync(z, 0, NK * sizeof(float), stream);

    attn_fused<<<dim3(KCHUNKS * B_ * (S_ / TQ)), dim3(256), 0, stream>>>(
        q, khi, klo, vt, mask, z, att);
}

// Round 7
// 518.877 us; speedup vs baseline: 1.1696x; 1.0543x over previous
//
#include <hip/hip_runtime.h>
#include <hip/hip_bf16.h>
#include <cmath>

#define B_ 2
#define H_ 8
#define S_ 2048
#define D_ 64
#define TQ 16
#define TK 64
#define KCHUNKS 8
#define TPC ((S_ / TK) / KCHUNKS)   // 4 k-tiles of 64 keys per chunk

typedef __bf16 bf16x8 __attribute__((ext_vector_type(8)));
typedef float  f32x4  __attribute__((ext_vector_type(4)));

// 272B rows = 17 x 16B units: odd unit count staggers banks across rows.
#define SB_STRIDE 68

#define NK ((size_t)B_ * H_ * S_ * D_)   // 2,097,152 elements

// ---------------- prep 1: K -> bf16 hi/lo (split-bf16 for fp32-grade QK) ----------------
__global__ __launch_bounds__(256)
void prep_k(const float* __restrict__ kg, __bf16* __restrict__ khi, __bf16* __restrict__ klo)
{
    const size_t i = ((size_t)blockIdx.x * 256 + threadIdx.x) * 8;
    float4 f0 = ((const float4*)(kg + i))[0];
    float4 f1 = ((const float4*)(kg + i))[1];
    float fv[8] = {f0.x, f0.y, f0.z, f0.w, f1.x, f1.y, f1.z, f1.w};
    bf16x8 hi, lo;
    #pragma unroll
    for (int j = 0; j < 8; ++j) {
        __bf16 h = (__bf16)fv[j];
        hi[j] = h;
        lo[j] = (__bf16)(fv[j] - (float)h);
    }
    *(bf16x8*)(khi + i) = hi;
    *(bf16x8*)(klo + i) = lo;
}

// ---------------- prep 2: V -> bf16 transposed vt[b][h][d][s] ----------------
__global__ __launch_bounds__(256)
void prep_vt(const float* __restrict__ vg, __bf16* __restrict__ vt)
{
    __shared__ float tile[64][65];
    const int bh = blockIdx.x >> 5;   // 0..15 = b*H+h
    const int kt = blockIdx.x & 31;   // 64-key tile
    const int t  = threadIdx.x;
    {
        const int key = t >> 2, seg = t & 3;
        const float* src = vg + ((size_t)bh * S_ + kt * 64 + key) * D_ + seg * 16;
        #pragma unroll
        for (int i = 0; i < 4; ++i) {
            float4 f = ((const float4*)src)[i];
            tile[key][seg * 16 + i * 4 + 0] = f.x;
            tile[key][seg * 16 + i * 4 + 1] = f.y;
            tile[key][seg * 16 + i * 4 + 2] = f.z;
            tile[key][seg * 16 + i * 4 + 3] = f.w;
        }
    }
    __syncthreads();
    {
        const int d = t >> 2, seg = t & 3;
        bf16x8 o0, o1;
        #pragma unroll
        for (int j = 0; j < 8; ++j) o0[j] = (__bf16)tile[seg * 16 + j][d];
        #pragma unroll
        for (int j = 0; j < 8; ++j) o1[j] = (__bf16)tile[seg * 16 + 8 + j][d];
        __bf16* dst = vt + ((size_t)bh * D_ + d) * S_ + kt * 64 + seg * 16;
        *(bf16x8*)dst       = o0;
        *((bf16x8*)dst + 1) = o1;
    }
}

// ---------------- main fused kernel ----------------
// (256,3): VGPR cap 170 (was 128 at (256,4)). Rounds 2-6 showed a constant
// ~60B/thread/iter scratch round-trip (+100-250MB HBM each way) that tracks
// iteration count, not code shape -- the live set (qhi/qlo 32 + acc 32 +
// softmax 32 + mask/addressing) sits right at the 128 cap. LDS (34.8KB) still
// allows 4 blocks/CU; VGPRs now limit to 3. Trading 25% occupancy for zero
// spill -- latency-bound kernel, but scratch wait-states dominate.
__global__ __launch_bounds__(256, 3)
void attn_fused(const float* __restrict__ qg,
                const __bf16* __restrict__ khi_g, const __bf16* __restrict__ klo_g,
                const __bf16* __restrict__ vt_g,  const int* __restrict__ maskg,
                float* __restrict__ zout, float* __restrict__ attout)
{
    // single LDS buffer: fp32 scores, then in-place swizzled bf16 att (34,816 B)
    __shared__ __align__(16) float sbuf[H_][TQ][SB_STRIDE];

    const int tid  = threadIdx.x;
    const int lane = tid & 63;
    const int wave = tid >> 6;      // wave handles heads 2w, 2w+1
    const int n16  = lane & 15;
    const int quad = lane >> 4;

    // ROUND-0 grid mapping (measured-good): chunk in HIGH bits. The 8 z-partials
    // of a q-tile land on the SAME XCD -> z atomics stay L2-local; each XCD holds
    // a small interleaved K/V hot set that survives L2.
    const int bi    = blockIdx.x;
    const int b     = bi & 1;
    const int qt    = (bi >> 1) & 127;
    const int chunk = bi >> 8;
    const int q0    = qt * TQ;

    const float scale = 0.35355339059327373f;  // 1/sqrt(H=8) -- k.shape[1] trap!

    // Q fragments, hi/lo split-bf16 (scaled), converted ONCE per block
    bf16x8 qhi[2][2], qlo[2][2];
    #pragma unroll
    for (int hh = 0; hh < 2; ++hh) {
        const int h = wave * 2 + hh;
        const float* qp = qg + (size_t)((b * H_ + h) * S_ + q0 + n16) * D_;
        #pragma unroll
        for (int kk = 0; kk < 2; ++kk) {
            const float4* p = (const float4*)(qp + kk * 32 + quad * 8);
            float4 f0 = p[0], f1 = p[1];
            float fv[8] = {f0.x, f0.y, f0.z, f0.w, f1.x, f1.y, f1.z, f1.w};
            bf16x8 hi, lo;
            #pragma unroll
            for (int j = 0; j < 8; ++j) {
                float fs = fv[j] * scale;
                __bf16 h16 = (__bf16)fs;
                hi[j] = h16;
                lo[j] = (__bf16)(fs - (float)h16);
            }
            qhi[hh][kk] = hi; qlo[hh][kk] = lo;
        }
    }

    f32x4 acc[2][4];
    #pragma unroll
    for (int hh = 0; hh < 2; ++hh)
        #pragma unroll
        for (int d = 0; d < 4; ++d)
            acc[hh][d] = (f32x4){0.f, 0.f, 0.f, 0.f};

    // softmax-phase mapping: one q-row + one float4 of 4 keys per thread
    const int sqq = tid >> 4;       // 0..15
    const int sk4 = tid & 15;       // 4-key column group

    const int* mrow = maskg + (size_t)(b * S_ + q0 + sqq) * S_ + chunk * (TK * TPC) + sk4 * 4;
    int4 mcur = *(const int4*)mrow;        // mask for kt=0, loaded before the loop

    for (int kt = 0; kt < TPC; ++kt) {
        const int k0 = chunk * (TK * TPC) + kt * TK;

        // prefetch next iteration's mask: a full iteration of latency hiding
        const int kn = (kt + 1 < TPC) ? (kt + 1) : kt;
        int4 mnext = *(const int4*)(mrow + kn * TK);

        __syncthreads();   // (b3) previous iteration's PV done reading sbuf
                           //      (first iter: trivial)

        // ---- QK^T: 3-term split-bf16 MFMA; scores written to LDS INLINE ----
        // (cc dies inside its ks iteration -- no accumulators across barriers)
        #pragma unroll
        for (int hh = 0; hh < 2; ++hh) {
            const int h = wave * 2 + hh;
            #pragma unroll
            for (int ks = 0; ks < 4; ++ks) {
                const size_t krow = ((size_t)(b * H_ + h) * S_ + k0 + ks * 16 + n16) * D_
                                    + quad * 8;
                f32x4 cc = (f32x4){0.f, 0.f, 0.f, 0.f};
                #pragma unroll
                for (int kk = 0; kk < 2; ++kk) {
                    bf16x8 khiv = *(const bf16x8*)(khi_g + krow + kk * 32);
                    bf16x8 klov = *(const bf16x8*)(klo_g + krow + kk * 32);
                    cc = __builtin_amdgcn_mfma_f32_16x16x32_bf16(qhi[hh][kk], khiv, cc, 0, 0, 0);
                    cc = __builtin_amdgcn_mfma_f32_16x16x32_bf16(qlo[hh][kk], khiv, cc, 0, 0, 0);
                    cc = __builtin_amdgcn_mfma_f32_16x16x32_bf16(qhi[hh][kk], klov, cc, 0, 0, 0);
                }
                #pragma unroll
                for (int r = 0; r < 4; ++r)
                    sbuf[h][quad * 4 + r][ks * 16 + n16] = cc[r];
            }
        }

        __syncthreads();   // (b1) scores visible to all waves

        // ---- softmax ACROSS HEADS (axis=1) + mask; att stored inline ----
        {
            f32x4 sv[H_];
            f32x4 mx = (f32x4){-INFINITY, -INFINITY, -INFINITY, -INFINITY};
            #pragma unroll
            for (int h = 0; h < H_; ++h) {
                sv[h] = *(const f32x4*)&sbuf[h][sqq][sk4 * 4];
                #pragma unroll
                for (int j = 0; j < 4; ++j) mx[j] = fmaxf(mx[j], sv[h][j]);
            }
            f32x4 sum = (f32x4){0.f, 0.f, 0.f, 0.f};
            #pragma unroll
            for (int h = 0; h < H_; ++h)
                #pragma unroll
                for (int j = 0; j < 4; ++j) {
                    sv[h][j] = __expf(sv[h][j] - mx[j]);
                    sum[j] += sv[h][j];
                }
            f32x4 inv;
            #pragma unroll
            for (int j = 0; j < 4; ++j) inv[j] = 1.0f / sum[j];
            const int mm[4] = {mcur.x, mcur.y, mcur.z, mcur.w};
            const int physw = ((sk4 >> 1) + 2 * (sqq & 3)) & 7;   // rotate-swizzle unit
            #pragma unroll
            for (int h = 0; h < H_; ++h) {
                f32x4 a;
                #pragma unroll
                for (int j = 0; j < 4; ++j)
                    // all-heads-masked => ties => uniform softmax = 1/8
                    a[j] = (mm[j] == 0) ? 0.125f : sv[h][j] * inv[j];
                // fp32 att -> global immediately (16B store, value then dead)
                *(f32x4*)&attout[(size_t)((b * H_ + h) * S_ + q0 + sqq) * S_ + k0 + sk4 * 4] = a;
                // pack 4 bf16 in-place. Safe: row sqq is touched only by 16
                // threads of ONE wave; per-wave LDS ops are in-order, and all
                // reads of plane h precede its writes in program order.
                union { __bf16 b4[4]; uint2 u2; } pk;
                #pragma unroll
                for (int j = 0; j < 4; ++j) pk.b4[j] = (__bf16)a[j];
                *(uint2*)((char*)&sbuf[h][sqq][0] + physw * 16 + (sk4 & 1) * 8) = pk.u2;
            }
        }

        __syncthreads();   // (b2) packed att visible

        // ---- PV: A = swizzled bf16 att from LDS, B = pre-transposed V^T ----
        #pragma unroll
        for (int hh = 0; hh < 2; ++hh) {
            const int h = wave * 2 + hh;
            #pragma unroll
            for (int kk = 0; kk < 2; ++kk) {
                const int physr = ((kk * 4 + quad) + 2 * (n16 & 3)) & 7;
                bf16x8 af = *(const bf16x8*)((const char*)&sbuf[h][n16][0] + physr * 16);
                #pragma unroll
                for (int dsb = 0; dsb < 4; ++dsb) {
                    bf16x8 bv = *(const bf16x8*)(vt_g
                        + ((size_t)(b * H_ + h) * D_ + dsb * 16 + n16) * S_
                        + k0 + kk * 32 + quad * 8);
                    acc[hh][dsb] = __builtin_amdgcn_mfma_f32_16x16x32_bf16(af, bv, acc[hh][dsb], 0, 0, 0);
                }
            }
        }

        mcur = mnext;
    }

    // ---- epilogue: accumulate partial z across k-chunks via device atomics ----
    // (all 8 chunk-partials of a q-tile map to the same XCD -> L2-local atomics)
    #pragma unroll
    for (int hh = 0; hh < 2; ++hh) {
        const int h = wave * 2 + hh;
        #pragma unroll
        for (int dsb = 0; dsb < 4; ++dsb)
            #pragma unroll
            for (int r = 0; r < 4; ++r)
                atomicAdd(&zout[(size_t)((b * H_ + h) * S_ + q0 + quad * 4 + r) * D_
                                + dsb * 16 + n16],
                          acc[hh][dsb][r]);
    }
}

extern "C" void kernel_launch(void* const* d_in, const int* in_sizes, int n_in,
                              void* d_out, int out_size, void* d_ws, size_t ws_size,
                              hipStream_t stream) {
    const float* q    = (const float*)d_in[0];
    const float* k    = (const float*)d_in[1];
    const float* v    = (const float*)d_in[2];
    const int*   mask = (const int*)d_in[3];
    float* z   = (float*)d_out;
    float* att = (float*)d_out + NK;   // outputs: (z, att_score)

    // workspace layout: khi | klo | vt   (bf16 each, NK elements) = 12.6 MB
    __bf16* khi = (__bf16*)d_ws;
    __bf16* klo = khi + NK;
    __bf16* vt  = klo + NK;

    prep_k <<<dim3(NK / (256 * 8)), dim3(256), 0, stream>>>(k, khi, klo);
    prep_vt<<<dim3(B_ * H_ * (S_ / 64)), dim3(256), 0, stream>>>(v, vt);

    // z accumulated atomically across 8 k-chunks -> must start at zero
    hipMemsetAsync(z, 0, NK * sizeof(float), stream);

    attn_fused<<<dim3(KCHUNKS * B_ * (S_ / TQ)), dim3(256), 0, stream>>>(
        q, khi, klo, vt, mask, z, att);
}